// Round 5
// baseline (659.190 us; speedup 1.0000x reference)
//
#include <hip/hip_runtime.h>
#include <hip/hip_bf16.h>

// Problem constants: T=512 tokens, D=2048 hidden, E=64 experts, K=8 top-k, F=768.
#define T_TOK 512
#define D_DIM 2048
#define E_NUM 64
#define K_TOP 8
#define F_DIM 768

typedef __bf16 bf16x8 __attribute__((ext_vector_type(8)));
typedef float  f32x4  __attribute__((ext_vector_type(4)));

// ---------------- workspace layout (bytes) ----------------
// cnt  : int[64]          @ 0
// ids  : int[64*512]      @ 4096
// pw   : float[4096]      @ 139264
// Xbf  : bf16[512*2048]   @ 155648   (2 MB)
// H    : bf16[4096*768]   @ 2252800  (6 MB)
// Y    : bf16[4096*2048]  @ 8544256  (16 MB)   total ~24.2 MB
#define WS_IDS   4096
#define WS_PW    139264
#define WS_XBF   155648
#define WS_H     2252800
#define WS_Y     8544256

__global__ void zero_cnt_kernel(int* __restrict__ cnt) {
    if (threadIdx.x < E_NUM) cnt[threadIdx.x] = 0;
}

// X fp32 -> bf16 pre-pass (makes MFMA A-frags direct uint4 loads)
__global__ __launch_bounds__(256) void xcvt_kernel(
        const float* __restrict__ x, __bf16* __restrict__ xb) {
    const size_t i = ((size_t)blockIdx.x * 256 + threadIdx.x) * 8;
    const float4 a = *(const float4*)(x + i);
    const float4 b = *(const float4*)(x + i + 4);
    bf16x8 v;
    v[0]=(__bf16)a.x; v[1]=(__bf16)a.y; v[2]=(__bf16)a.z; v[3]=(__bf16)a.w;
    v[4]=(__bf16)b.x; v[5]=(__bf16)b.y; v[6]=(__bf16)b.z; v[7]=(__bf16)b.w;
    *(uint4*)(xb + i) = __builtin_bit_cast(uint4, v);
}

// ---------------- router: logits -> softmax -> top-8 -> renorm ----------------
__global__ __launch_bounds__(256) void router_kernel(
        const float* __restrict__ x, const float* __restrict__ gw,
        float* __restrict__ pair_w, int* __restrict__ cnt, int* __restrict__ ids) {
    const int t   = blockIdx.x;
    const int tid = threadIdx.x;
    const int e   = tid & 63;
    const int c   = tid >> 6;
    const float* xr = x + (size_t)t * D_DIM;
    const int k0 = c * (D_DIM / 4);
    float s = 0.f;
    #pragma unroll 8
    for (int k = 0; k < D_DIM / 4; k++) {
        s += xr[k0 + k] * gw[(size_t)(k0 + k) * E_NUM + e];
    }
    __shared__ float part[4][64];
    part[c][e] = s;
    __syncthreads();
    if (tid < 64) {  // first wave only; lane == e
        float logit = part[0][e] + part[1][e] + part[2][e] + part[3][e];
        float cur = logit;
        float selV[8]; int selE[8];
        #pragma unroll
        for (int i = 0; i < 8; i++) {
            float bv = cur; int bi = e;
            #pragma unroll
            for (int off = 32; off > 0; off >>= 1) {
                float ov = __shfl_xor(bv, off);
                int   oi = __shfl_xor(bi, off);
                if (ov > bv || (ov == bv && oi < bi)) { bv = ov; bi = oi; }
            }
            selV[i] = bv; selE[i] = bi;
            if (e == bi) cur = -INFINITY;
        }
        const float m = selV[0];
        float sum = 0.f;
        #pragma unroll
        for (int i = 0; i < 8; i++) sum += __expf(selV[i] - m);
        float myW = 0.f; int myE = 0;
        #pragma unroll
        for (int i = 0; i < 8; i++) {
            if (e == i) { myW = __expf(selV[i] - m) / sum; myE = selE[i]; }
        }
        if (e < 8) {
            pair_w[t * K_TOP + e] = myW;
            int pos = atomicAdd(&cnt[myE], 1);
            ids[myE * T_TOK + pos] = t * K_TOP + e;  // token = id>>3
        }
    }
}

// ================= mlp1: H[pair] = silu(X@Wg) * (X@Wu) =================
// BN=32 (tile row = 128B = one L2 line), waves split K in halves: wave w has
// K-half h=w>>1, col-half cg=w&1. Each wave is a fully independent,
// barrier-free load stream (16 B-dwords + 4 A-uint4 per k-step). One LDS
// reduce across K-halves at the end, then silu. mtile loop inside the block.
__global__ __launch_bounds__(256, 4) void mlp1_kernel(
        const __bf16* __restrict__ xb,
        const float* __restrict__ w_gate, const float* __restrict__ w_up,
        const int* __restrict__ cnt, const int* __restrict__ ids,
        __bf16* __restrict__ H) {
    const int e  = blockIdx.y;
    const int ft = blockIdx.x;      // 24 tiles of 32 cols
    const int n  = cnt[e];

    const int tid  = threadIdx.x;
    const int lane = tid & 63;
    const int w    = tid >> 6;
    const int h    = w >> 1;        // K-half
    const int cg   = w & 1;         // col-half (16 cols)
    const int g16  = lane >> 4;
    const int l16  = lane & 15;

    __shared__ __align__(16) f32x4 red[16][64];  // 16 KB reduce buffer

    const int fcol = ft * 32 + cg * 16 + l16;
    const size_t bbase = (size_t)e * D_DIM * F_DIM
                       + (size_t)(h * 1024 + g16 * 8) * F_DIM + fcol;
    const float* bg = w_gate + bbase;
    const float* bu = w_up   + bbase;

    for (int mt = 0; mt * 64 < n; mt++) {
        // A row pointers: row = mt*64 + m*16 + l16, k-chunk = h*1024 + g16*8
        const __bf16* arow[4];
        #pragma unroll
        for (int m = 0; m < 4; m++) {
            const int p   = mt * 64 + m * 16 + l16;
            const int tok = (p < n) ? (ids[e * T_TOK + p] >> 3) : 0;
            arow[m] = xb + (size_t)tok * D_DIM + h * 1024 + g16 * 8;
        }

        f32x4 accg[4], accu[4];
        #pragma unroll
        for (int m = 0; m < 4; m++) {
            accg[m][0]=0.f; accg[m][1]=0.f; accg[m][2]=0.f; accg[m][3]=0.f;
            accu[m][0]=0.f; accu[m][1]=0.f; accu[m][2]=0.f; accu[m][3]=0.f;
        }

        #pragma unroll 2
        for (int ks = 0; ks < 32; ks++) {   // K-half = 1024 = 32 steps of 32
            float gv[8], uv[8];
            #pragma unroll
            for (int i = 0; i < 8; i++) gv[i] = bg[(ks * 32 + i) * F_DIM];
            #pragma unroll
            for (int i = 0; i < 8; i++) uv[i] = bu[(ks * 32 + i) * F_DIM];
            uint4 av[4];
            #pragma unroll
            for (int m = 0; m < 4; m++) av[m] = *(const uint4*)(arow[m] + ks * 32);
            bf16x8 bgf, buf8;
            #pragma unroll
            for (int i = 0; i < 8; i++) { bgf[i] = (__bf16)gv[i]; buf8[i] = (__bf16)uv[i]; }
            #pragma unroll
            for (int m = 0; m < 4; m++) {
                accg[m] = __builtin_amdgcn_mfma_f32_16x16x32_bf16(
                    __builtin_bit_cast(bf16x8, av[m]), bgf,  accg[m], 0, 0, 0);
                accu[m] = __builtin_amdgcn_mfma_f32_16x16x32_bf16(
                    __builtin_bit_cast(bf16x8, av[m]), buf8, accu[m], 0, 0, 0);
            }
        }

        // reduce K-halves: h=1 waves publish, h=0 waves add + silu + store
        if (h == 1) {
            #pragma unroll
            for (int m = 0; m < 4; m++) {
                red[cg * 8 + m][lane]     = accg[m];
                red[cg * 8 + 4 + m][lane] = accu[m];
            }
        }
        __syncthreads();
        if (h == 0) {
            #pragma unroll
            for (int m = 0; m < 4; m++) {
                const f32x4 pg = red[cg * 8 + m][lane];
                const f32x4 pu = red[cg * 8 + 4 + m][lane];
                #pragma unroll
                for (int r = 0; r < 4; r++) {
                    const int p = mt * 64 + m * 16 + g16 * 4 + r;
                    if (p < n) {
                        const int rid = ids[e * T_TOK + p];
                        const float g = accg[m][r] + pg[r];
                        const float u = accu[m][r] + pu[r];
                        const float hv = (g / (1.f + __expf(-g))) * u;
                        H[(size_t)rid * F_DIM + fcol] = (__bf16)hv;
                    }
                }
            }
        }
        __syncthreads();  // red[] safe to reuse next mt
    }
}

// ================= mlp2: Y[pair] = H @ Wd =================
// Same structure: BN=32 over D (64 tiles), K=F=768 split in halves (384/wave).
__global__ __launch_bounds__(256, 4) void mlp2_kernel(
        const __bf16* __restrict__ H, const float* __restrict__ w_down,
        const int* __restrict__ cnt, const int* __restrict__ ids,
        __bf16* __restrict__ Y) {
    const int e  = blockIdx.y;
    const int dt = blockIdx.x;      // 64 tiles of 32 cols
    const int n  = cnt[e];

    const int tid  = threadIdx.x;
    const int lane = tid & 63;
    const int w    = tid >> 6;
    const int h    = w >> 1;
    const int cg   = w & 1;
    const int g16  = lane >> 4;
    const int l16  = lane & 15;

    __shared__ __align__(16) f32x4 red[8][64];   // 8 KB

    const int dcol = dt * 32 + cg * 16 + l16;
    const float* bd = w_down + (size_t)e * F_DIM * D_DIM
                    + (size_t)(h * 384 + g16 * 8) * D_DIM + dcol;

    for (int mt = 0; mt * 64 < n; mt++) {
        const __bf16* arow[4];
        #pragma unroll
        for (int m = 0; m < 4; m++) {
            const int p   = mt * 64 + m * 16 + l16;
            const int rid = (p < n) ? ids[e * T_TOK + p] : 0;
            arow[m] = H + (size_t)rid * F_DIM + h * 384 + g16 * 8;
        }

        f32x4 acc[4];
        #pragma unroll
        for (int m = 0; m < 4; m++) { acc[m][0]=0.f; acc[m][1]=0.f; acc[m][2]=0.f; acc[m][3]=0.f; }

        #pragma unroll 2
        for (int ks = 0; ks < 12; ks++) {   // K-half = 384 = 12 steps of 32
            float dv[8];
            #pragma unroll
            for (int i = 0; i < 8; i++) dv[i] = bd[(ks * 32 + i) * D_DIM];
            uint4 av[4];
            #pragma unroll
            for (int m = 0; m < 4; m++) av[m] = *(const uint4*)(arow[m] + ks * 32);
            bf16x8 bdf;
            #pragma unroll
            for (int i = 0; i < 8; i++) bdf[i] = (__bf16)dv[i];
            #pragma unroll
            for (int m = 0; m < 4; m++) {
                acc[m] = __builtin_amdgcn_mfma_f32_16x16x32_bf16(
                    __builtin_bit_cast(bf16x8, av[m]), bdf, acc[m], 0, 0, 0);
            }
        }

        if (h == 1) {
            #pragma unroll
            for (int m = 0; m < 4; m++) red[cg * 4 + m][lane] = acc[m];
        }
        __syncthreads();
        if (h == 0) {
            #pragma unroll
            for (int m = 0; m < 4; m++) {
                const f32x4 pr = red[cg * 4 + m][lane];
                #pragma unroll
                for (int r = 0; r < 4; r++) {
                    const int p = mt * 64 + m * 16 + g16 * 4 + r;
                    if (p < n) {
                        const int rid = ids[e * T_TOK + p];
                        Y[(size_t)rid * D_DIM + dcol] = (__bf16)(acc[m][r] + pr[r]);
                    }
                }
            }
        }
        __syncthreads();
    }
}

// ---------------- combine: out[t] = sum_k w[t,k] * Y[t*8+k] ----------------
__global__ __launch_bounds__(256) void combine_kernel(
        const __bf16* __restrict__ Y, const float* __restrict__ pw,
        float* __restrict__ out) {
    const int t   = blockIdx.x;
    const int tid = threadIdx.x;
    const int d0  = tid * 8;
    float acc[8];
    #pragma unroll
    for (int j = 0; j < 8; j++) acc[j] = 0.f;
    #pragma unroll
    for (int k = 0; k < K_TOP; k++) {
        const float wgt = pw[t * K_TOP + k];
        bf16x8 v = *(const bf16x8*)(Y + (size_t)(t * K_TOP + k) * D_DIM + d0);
        #pragma unroll
        for (int j = 0; j < 8; j++) acc[j] += wgt * (float)v[j];
    }
    #pragma unroll
    for (int j = 0; j < 8; j++) out[(size_t)t * D_DIM + d0 + j] = acc[j];
}

extern "C" void kernel_launch(void* const* d_in, const int* in_sizes, int n_in,
                              void* d_out, int out_size, void* d_ws, size_t ws_size,
                              hipStream_t stream) {
    const float* x      = (const float*)d_in[0];
    const float* gw     = (const float*)d_in[1];
    const float* w_gate = (const float*)d_in[2];
    const float* w_up   = (const float*)d_in[3];
    const float* w_down = (const float*)d_in[4];
    float* out = (float*)d_out;

    char* ws = (char*)d_ws;
    int*    cnt = (int*)(ws);
    int*    ids = (int*)(ws + WS_IDS);
    float*  pw  = (float*)(ws + WS_PW);
    __bf16* xbf = (__bf16*)(ws + WS_XBF);
    __bf16* H   = (__bf16*)(ws + WS_H);
    __bf16* Y   = (__bf16*)(ws + WS_Y);

    zero_cnt_kernel<<<1, 64, 0, stream>>>(cnt);
    xcvt_kernel<<<T_TOK * D_DIM / (256 * 8), 256, 0, stream>>>(x, xbf);
    router_kernel<<<T_TOK, 256, 0, stream>>>(x, gw, pw, cnt, ids);
    mlp1_kernel<<<dim3(F_DIM / 32, E_NUM), 256, 0, stream>>>(xbf, w_gate, w_up, cnt, ids, H);
    mlp2_kernel<<<dim3(D_DIM / 32, E_NUM), 256, 0, stream>>>(H, w_down, cnt, ids, Y);
    combine_kernel<<<T_TOK, 256, 0, stream>>>(Y, pw, out);
}

// Round 6
// 415.499 us; speedup vs baseline: 1.5865x; 1.5865x over previous
//
#include <hip/hip_runtime.h>
#include <hip/hip_bf16.h>

// Problem constants: T=512 tokens, D=2048 hidden, E=64 experts, K=8 top-k, F=768.
#define T_TOK 512
#define D_DIM 2048
#define E_NUM 64
#define K_TOP 8
#define F_DIM 768

typedef __bf16 bf16x8 __attribute__((ext_vector_type(8)));
typedef float  f32x4  __attribute__((ext_vector_type(4)));

#define AS1 __attribute__((address_space(1)))
#define AS3 __attribute__((address_space(3)))

// async global->LDS, 16B/lane; LDS dest = wave-uniform base + lane*16.
__device__ __forceinline__ void gll16(const void* g, void* l) {
    __builtin_amdgcn_global_load_lds((const AS1 uint32_t*)g, (AS3 uint32_t*)l, 16, 0, 0);
}

#define VM_WAIT_I(N) asm volatile("s_waitcnt vmcnt(" #N ")" ::: "memory")
#define VM_WAIT(N) VM_WAIT_I(N)

// One pipeline step: wait for group's loads, sync, consume buffer, sync,
// optionally stage the next group into the freed buffer.
#define PIPE_STEP(WN, BUF, DOSTG, KN)            \
    do {                                          \
        VM_WAIT(WN);                              \
        __builtin_amdgcn_sched_barrier(0);        \
        __builtin_amdgcn_s_barrier();             \
        consume(BUF);                             \
        __builtin_amdgcn_s_barrier();             \
        __builtin_amdgcn_sched_barrier(0);        \
        if (DOSTG) stage(BUF, KN);                \
    } while (0)

// ---------------- workspace layout (bytes) ----------------
// cnt  : int[64]          @ 0
// ids  : int[64*512]      @ 4096
// pw   : float[4096]      @ 139264
// Xbf  : bf16[512*2048]   @ 155648   (2 MB)
// H    : bf16[4096*768]   @ 2252800  (6 MB)
// Y    : bf16[4096*2048]  @ 8544256  (16 MB)
#define WS_IDS   4096
#define WS_PW    139264
#define WS_XBF   155648
#define WS_H     2252800
#define WS_Y     8544256

__global__ void zero_cnt_kernel(int* __restrict__ cnt) {
    if (threadIdx.x < E_NUM) cnt[threadIdx.x] = 0;
}

// X fp32 -> bf16 pre-pass
__global__ __launch_bounds__(256) void xcvt_kernel(
        const float* __restrict__ x, __bf16* __restrict__ xb) {
    const size_t i = ((size_t)blockIdx.x * 256 + threadIdx.x) * 8;
    const float4 a = *(const float4*)(x + i);
    const float4 b = *(const float4*)(x + i + 4);
    bf16x8 v;
    v[0]=(__bf16)a.x; v[1]=(__bf16)a.y; v[2]=(__bf16)a.z; v[3]=(__bf16)a.w;
    v[4]=(__bf16)b.x; v[5]=(__bf16)b.y; v[6]=(__bf16)b.z; v[7]=(__bf16)b.w;
    *(uint4*)(xb + i) = __builtin_bit_cast(uint4, v);
}

// ---------------- router: logits -> softmax -> top-8 -> renorm ----------------
__global__ __launch_bounds__(256) void router_kernel(
        const float* __restrict__ x, const float* __restrict__ gw,
        float* __restrict__ pair_w, int* __restrict__ cnt, int* __restrict__ ids) {
    const int t   = blockIdx.x;
    const int tid = threadIdx.x;
    const int e   = tid & 63;
    const int c   = tid >> 6;
    const float* xr = x + (size_t)t * D_DIM;
    const int k0 = c * (D_DIM / 4);
    float s = 0.f;
    #pragma unroll 8
    for (int k = 0; k < D_DIM / 4; k++) {
        s += xr[k0 + k] * gw[(size_t)(k0 + k) * E_NUM + e];
    }
    __shared__ float part[4][64];
    part[c][e] = s;
    __syncthreads();
    if (tid < 64) {  // first wave only; lane == e
        float logit = part[0][e] + part[1][e] + part[2][e] + part[3][e];
        float cur = logit;
        float selV[8]; int selE[8];
        #pragma unroll
        for (int i = 0; i < 8; i++) {
            float bv = cur; int bi = e;
            #pragma unroll
            for (int off = 32; off > 0; off >>= 1) {
                float ov = __shfl_xor(bv, off);
                int   oi = __shfl_xor(bi, off);
                if (ov > bv || (ov == bv && oi < bi)) { bv = ov; bi = oi; }
            }
            selV[i] = bv; selE[i] = bi;
            if (e == bi) cur = -INFINITY;
        }
        const float m = selV[0];
        float sum = 0.f;
        #pragma unroll
        for (int i = 0; i < 8; i++) sum += __expf(selV[i] - m);
        float myW = 0.f; int myE = 0;
        #pragma unroll
        for (int i = 0; i < 8; i++) {
            if (e == i) { myW = __expf(selV[i] - m) / sum; myE = selE[i]; }
        }
        if (e < 8) {
            pair_w[t * K_TOP + e] = myW;
            int pos = atomicAdd(&cnt[myE], 1);
            ids[myE * T_TOK + pos] = t * K_TOP + e;  // token = id>>3
        }
    }
}

// ================= mlp1: H[pair] = silu(X@Wg) * (X@Wu) =================
// BM=128, BN=32, BK=32. ALL loads via global_load_lds into a 4-buffer LDS
// ring (zero dest-VGPR loads in the k-loop). Counted vmcnt keeps 3 k-steps
// (48 KB/block) in flight. Wave w: rows 64*(w>>1)+[0,64), cols 16*(w&1)+[0,16).
// Buffer layout (16 KB): A bf16 [chunk4][row128]*16B | Bg f32 [k32][col32] | Bu.
__global__ __launch_bounds__(256, 2) void mlp1_kernel(
        const __bf16* __restrict__ xb,
        const float* __restrict__ w_gate, const float* __restrict__ w_up,
        const int* __restrict__ cnt, const int* __restrict__ ids,
        __bf16* __restrict__ H) {
    const int e  = blockIdx.y;
    const int ft = blockIdx.x;      // 24 tiles of 32 cols
    const int n  = cnt[e];
    if (n <= 0) return;

    const int tid  = threadIdx.x;
    const int lane = tid & 63;
    const int w    = tid >> 6;
    const int g16  = lane >> 4;
    const int l16  = lane & 15;
    const int mblk = w >> 1;        // row-half
    const int cg   = w & 1;         // col-half

    __shared__ __align__(16) char lds[4][16384];

    // B staging source: thread covers k=tid>>3, cols (tid&7)*4..+4
    const int bk  = tid >> 3;
    const int bc4 = tid & 7;
    const float* bgs = w_gate + (size_t)e * D_DIM * F_DIM + (size_t)bk * F_DIM + ft * 32 + bc4 * 4;
    const float* bus = w_up   + (size_t)e * D_DIM * F_DIM + (size_t)bk * F_DIM + ft * 32 + bc4 * 4;
    const int fcol = ft * 32 + cg * 16 + l16;
    const int ch0  = tid >> 7;      // A staging chunk for j=0 (j=1: ch0+2)
    const int wb   = w * 1024;      // wave-uniform LDS byte base

    for (int mt = 0; mt * 128 < n; mt++) {
        // A staging source row (one token per thread; j=0/1 share the row)
        const int ap   = mt * 128 + (tid & 127);
        const int tok  = ids[(size_t)e * T_TOK + (ap < n ? ap : n - 1)] >> 3;
        const __bf16* asrc = xb + (size_t)tok * D_DIM;

        f32x4 accg[4], accu[4];
        #pragma unroll
        for (int m = 0; m < 4; m++) {
            accg[m][0]=0.f; accg[m][1]=0.f; accg[m][2]=0.f; accg[m][3]=0.f;
            accu[m][0]=0.f; accu[m][1]=0.f; accu[m][2]=0.f; accu[m][3]=0.f;
        }

        auto stage = [&](int buf, int ks) {   // 4 gll per thread
            char* L = lds[buf];
            gll16(asrc + ks * 32 + ch0 * 8,       L + wb);            // A chunk ch0
            gll16(asrc + ks * 32 + (ch0 + 2) * 8, L + 4096 + wb);     // A chunk ch0+2
            gll16(bgs + (size_t)ks * 32 * F_DIM,  L + 8192 + wb);     // B gate
            gll16(bus + (size_t)ks * 32 * F_DIM,  L + 12288 + wb);    // B up
        };
        auto consume = [&](int buf) {
            const char* L = lds[buf];
            const float* Bg = (const float*)(L + 8192);
            const float* Bu = (const float*)(L + 12288);
            bf16x8 bgf, buf8;
            #pragma unroll
            for (int i = 0; i < 8; i++) {
                bgf[i]  = (__bf16)Bg[(g16 * 8 + i) * 32 + cg * 16 + l16];
                buf8[i] = (__bf16)Bu[(g16 * 8 + i) * 32 + cg * 16 + l16];
            }
            #pragma unroll
            for (int m = 0; m < 4; m++) {
                const int row = mblk * 64 + m * 16 + l16;
                bf16x8 af = __builtin_bit_cast(bf16x8,
                    *(const uint4*)(L + (g16 * 128 + row) * 16));
                accg[m] = __builtin_amdgcn_mfma_f32_16x16x32_bf16(af, bgf,  accg[m], 0, 0, 0);
                accu[m] = __builtin_amdgcn_mfma_f32_16x16x32_bf16(af, buf8, accu[m], 0, 0, 0);
            }
        };

        // prologue: fill the ring (16 gll)
        stage(0, 0); stage(1, 1); stage(2, 2); stage(3, 3);

        for (int ks = 0; ks < 60; ks++) {       // NK=64, main 0..59
            PIPE_STEP(12, ks & 3, true, ks + 4);
        }
        PIPE_STEP(12, 0, false, 0);
        PIPE_STEP(8,  1, false, 0);
        PIPE_STEP(4,  2, false, 0);
        PIPE_STEP(0,  3, false, 0);

        // epilogue: h = silu(g)*u
        #pragma unroll
        for (int m = 0; m < 4; m++) {
            #pragma unroll
            for (int r = 0; r < 4; r++) {
                const int p = mt * 128 + mblk * 64 + m * 16 + g16 * 4 + r;
                if (p < n) {
                    const int rid = ids[(size_t)e * T_TOK + p];
                    const float g = accg[m][r], u = accu[m][r];
                    const float hv = (g / (1.f + __expf(-g))) * u;
                    H[(size_t)rid * F_DIM + fcol] = (__bf16)hv;
                }
            }
        }
    }
}

// ================= mlp2: Y[pair] = H @ Wd =================
// Same ring; 3 gll/group (A 2, B 1); buffer 12 KB: A bf16 8K | Bd f32 4K.
__global__ __launch_bounds__(256, 3) void mlp2_kernel(
        const __bf16* __restrict__ H, const float* __restrict__ w_down,
        const int* __restrict__ cnt, const int* __restrict__ ids,
        __bf16* __restrict__ Y) {
    const int e  = blockIdx.y;
    const int dt = blockIdx.x;      // 64 tiles of 32 cols
    const int n  = cnt[e];
    if (n <= 0) return;

    const int tid  = threadIdx.x;
    const int lane = tid & 63;
    const int w    = tid >> 6;
    const int g16  = lane >> 4;
    const int l16  = lane & 15;
    const int mblk = w >> 1;
    const int cg   = w & 1;

    __shared__ __align__(16) char lds[4][12288];

    const int bk  = tid >> 3;
    const int bc4 = tid & 7;
    const float* bds = w_down + (size_t)e * F_DIM * D_DIM + (size_t)bk * D_DIM + dt * 32 + bc4 * 4;
    const int dcol = dt * 32 + cg * 16 + l16;
    const int ch0  = tid >> 7;
    const int wb   = w * 1024;

    for (int mt = 0; mt * 128 < n; mt++) {
        const int ap  = mt * 128 + (tid & 127);
        const int rid0 = ids[(size_t)e * T_TOK + (ap < n ? ap : n - 1)];
        const __bf16* asrc = H + (size_t)rid0 * F_DIM;

        f32x4 acc[4];
        #pragma unroll
        for (int m = 0; m < 4; m++) { acc[m][0]=0.f; acc[m][1]=0.f; acc[m][2]=0.f; acc[m][3]=0.f; }

        auto stage = [&](int buf, int ks) {   // 3 gll per thread
            char* L = lds[buf];
            gll16(asrc + ks * 32 + ch0 * 8,       L + wb);
            gll16(asrc + ks * 32 + (ch0 + 2) * 8, L + 4096 + wb);
            gll16(bds + (size_t)ks * 32 * D_DIM,  L + 8192 + wb);
        };
        auto consume = [&](int buf) {
            const char* L = lds[buf];
            const float* Bd = (const float*)(L + 8192);
            bf16x8 bdf;
            #pragma unroll
            for (int i = 0; i < 8; i++)
                bdf[i] = (__bf16)Bd[(g16 * 8 + i) * 32 + cg * 16 + l16];
            #pragma unroll
            for (int m = 0; m < 4; m++) {
                const int row = mblk * 64 + m * 16 + l16;
                bf16x8 af = __builtin_bit_cast(bf16x8,
                    *(const uint4*)(L + (g16 * 128 + row) * 16));
                acc[m] = __builtin_amdgcn_mfma_f32_16x16x32_bf16(af, bdf, acc[m], 0, 0, 0);
            }
        };

        stage(0, 0); stage(1, 1); stage(2, 2); stage(3, 3);

        for (int ks = 0; ks < 20; ks++) {       // NK=24, main 0..19
            PIPE_STEP(9, ks & 3, true, ks + 4);
        }
        PIPE_STEP(9, 0, false, 0);
        PIPE_STEP(6, 1, false, 0);
        PIPE_STEP(3, 2, false, 0);
        PIPE_STEP(0, 3, false, 0);

        #pragma unroll
        for (int m = 0; m < 4; m++) {
            #pragma unroll
            for (int r = 0; r < 4; r++) {
                const int p = mt * 128 + mblk * 64 + m * 16 + g16 * 4 + r;
                if (p < n) {
                    const int rid = ids[(size_t)e * T_TOK + p];
                    Y[(size_t)rid * D_DIM + dcol] = (__bf16)acc[m][r];
                }
            }
        }
    }
}

// ---------------- combine: out[t] = sum_k w[t,k] * Y[t*8+k] ----------------
__global__ __launch_bounds__(256) void combine_kernel(
        const __bf16* __restrict__ Y, const float* __restrict__ pw,
        float* __restrict__ out) {
    const int t   = blockIdx.x;
    const int tid = threadIdx.x;
    const int d0  = tid * 8;
    float acc[8];
    #pragma unroll
    for (int j = 0; j < 8; j++) acc[j] = 0.f;
    #pragma unroll
    for (int k = 0; k < K_TOP; k++) {
        const float wgt = pw[t * K_TOP + k];
        bf16x8 v = *(const bf16x8*)(Y + (size_t)(t * K_TOP + k) * D_DIM + d0);
        #pragma unroll
        for (int j = 0; j < 8; j++) acc[j] += wgt * (float)v[j];
    }
    #pragma unroll
    for (int j = 0; j < 8; j++) out[(size_t)t * D_DIM + d0 + j] = acc[j];
}

extern "C" void kernel_launch(void* const* d_in, const int* in_sizes, int n_in,
                              void* d_out, int out_size, void* d_ws, size_t ws_size,
                              hipStream_t stream) {
    const float* x      = (const float*)d_in[0];
    const float* gw     = (const float*)d_in[1];
    const float* w_gate = (const float*)d_in[2];
    const float* w_up   = (const float*)d_in[3];
    const float* w_down = (const float*)d_in[4];
    float* out = (float*)d_out;

    char* ws = (char*)d_ws;
    int*    cnt = (int*)(ws);
    int*    ids = (int*)(ws + WS_IDS);
    float*  pw  = (float*)(ws + WS_PW);
    __bf16* xbf = (__bf16*)(ws + WS_XBF);
    __bf16* H   = (__bf16*)(ws + WS_H);
    __bf16* Y   = (__bf16*)(ws + WS_Y);

    zero_cnt_kernel<<<1, 64, 0, stream>>>(cnt);
    xcvt_kernel<<<T_TOK * D_DIM / (256 * 8), 256, 0, stream>>>(x, xbf);
    router_kernel<<<T_TOK, 256, 0, stream>>>(x, gw, pw, cnt, ids);
    mlp1_kernel<<<dim3(F_DIM / 32, E_NUM), 256, 0, stream>>>(xbf, w_gate, w_up, cnt, ids, H);
    mlp2_kernel<<<dim3(D_DIM / 32, E_NUM), 256, 0, stream>>>(H, w_down, cnt, ids, Y);
    combine_kernel<<<T_TOK, 256, 0, stream>>>(Y, pw, out);
}

// Round 7
// 385.049 us; speedup vs baseline: 1.7120x; 1.0791x over previous
//
#include <hip/hip_runtime.h>
#include <hip/hip_bf16.h>

// Problem constants: T=512 tokens, D=2048 hidden, E=64 experts, K=8 top-k, F=768.
#define T_TOK 512
#define D_DIM 2048
#define E_NUM 64
#define K_TOP 8
#define F_DIM 768

typedef __bf16 bf16x8 __attribute__((ext_vector_type(8)));
typedef float  f32x4  __attribute__((ext_vector_type(4)));

#define AS1 __attribute__((address_space(1)))
#define AS3 __attribute__((address_space(3)))

// async global->LDS, 16B/lane; LDS dest = wave-uniform base + lane*16.
__device__ __forceinline__ void gll16(const void* g, void* l) {
    __builtin_amdgcn_global_load_lds((const AS1 uint32_t*)g, (AS3 uint32_t*)l, 16, 0, 0);
}

#define VM_WAIT_I(N) asm volatile("s_waitcnt vmcnt(" #N ")" ::: "memory")
#define VM_WAIT(N) VM_WAIT_I(N)

// wait for step's 4 glls, sync, consume, sync, optionally stage next step.
#define PIPE_STEP(WN, BUF, DOSTG, KN)            \
    do {                                          \
        VM_WAIT(WN);                              \
        __builtin_amdgcn_sched_barrier(0);        \
        __builtin_amdgcn_s_barrier();             \
        consume(BUF);                             \
        __builtin_amdgcn_s_barrier();             \
        __builtin_amdgcn_sched_barrier(0);        \
        if (DOSTG) stage(BUF, KN);                \
    } while (0)

// ---------------- workspace layout (bytes) ----------------
// cnt  : int[64]          @ 0
// ids  : int[64*512]      @ 4096
// pw   : float[4096]      @ 139264
// Xbf  : bf16[512*2048]   @ 155648   (2 MB)
// H    : bf16[4096*768]   @ 2252800  (6 MB)
// Y    : bf16[4096*2048]  @ 8544256  (16 MB)
// G    : bf16[4096*768]   aliases Y (G is dead before mlp2 writes Y)
#define WS_IDS   4096
#define WS_PW    139264
#define WS_XBF   155648
#define WS_H     2252800
#define WS_Y     8544256

__global__ void zero_cnt_kernel(int* __restrict__ cnt) {
    if (threadIdx.x < E_NUM) cnt[threadIdx.x] = 0;
}

// X fp32 -> bf16 pre-pass
__global__ __launch_bounds__(256) void xcvt_kernel(
        const float* __restrict__ x, __bf16* __restrict__ xb) {
    const size_t i = ((size_t)blockIdx.x * 256 + threadIdx.x) * 8;
    const float4 a = *(const float4*)(x + i);
    const float4 b = *(const float4*)(x + i + 4);
    bf16x8 v;
    v[0]=(__bf16)a.x; v[1]=(__bf16)a.y; v[2]=(__bf16)a.z; v[3]=(__bf16)a.w;
    v[4]=(__bf16)b.x; v[5]=(__bf16)b.y; v[6]=(__bf16)b.z; v[7]=(__bf16)b.w;
    *(uint4*)(xb + i) = __builtin_bit_cast(uint4, v);
}

// ---------------- router: logits -> softmax -> top-8 -> renorm ----------------
__global__ __launch_bounds__(256) void router_kernel(
        const float* __restrict__ x, const float* __restrict__ gw,
        float* __restrict__ pair_w, int* __restrict__ cnt, int* __restrict__ ids) {
    const int t   = blockIdx.x;
    const int tid = threadIdx.x;
    const int e   = tid & 63;
    const int c   = tid >> 6;
    const float* xr = x + (size_t)t * D_DIM;
    const int k0 = c * (D_DIM / 4);
    float s = 0.f;
    #pragma unroll 8
    for (int k = 0; k < D_DIM / 4; k++) {
        s += xr[k0 + k] * gw[(size_t)(k0 + k) * E_NUM + e];
    }
    __shared__ float part[4][64];
    part[c][e] = s;
    __syncthreads();
    if (tid < 64) {  // first wave only; lane == e
        float logit = part[0][e] + part[1][e] + part[2][e] + part[3][e];
        float cur = logit;
        float selV[8]; int selE[8];
        #pragma unroll
        for (int i = 0; i < 8; i++) {
            float bv = cur; int bi = e;
            #pragma unroll
            for (int off = 32; off > 0; off >>= 1) {
                float ov = __shfl_xor(bv, off);
                int   oi = __shfl_xor(bi, off);
                if (ov > bv || (ov == bv && oi < bi)) { bv = ov; bi = oi; }
            }
            selV[i] = bv; selE[i] = bi;
            if (e == bi) cur = -INFINITY;
        }
        const float m = selV[0];
        float sum = 0.f;
        #pragma unroll
        for (int i = 0; i < 8; i++) sum += __expf(selV[i] - m);
        float myW = 0.f; int myE = 0;
        #pragma unroll
        for (int i = 0; i < 8; i++) {
            if (e == i) { myW = __expf(selV[i] - m) / sum; myE = selE[i]; }
        }
        if (e < 8) {
            pair_w[t * K_TOP + e] = myW;
            int pos = atomicAdd(&cnt[myE], 1);
            ids[myE * T_TOK + pos] = t * K_TOP + e;  // token = id>>3
        }
    }
}

// ================= unified expert GEMM pass =================
// C[rows n][64-col tile] = A[rows][KDIM] @ B_e[KDIM][BSTR], BM=128, BK=32.
// Ring-3 LDS (48 KB -> 3 blocks/CU), 4 gll/step (A 2 + B 2), steady vmcnt(8)
// = 2 full k-steps in flight. B k-row = 64 f32 = 256 B = one DRAM granule.
// MODE 0: Out = acc (gate pass -> G)
// MODE 1: Out = silu(Gin) * acc (up pass -> H)
// MODE 2: Out = acc (down pass -> Y)
template<int KDIM, int ASTR, int BSTR, int MODE>
__global__ __launch_bounds__(256, 3) void gemm_kernel(
        const __bf16* __restrict__ Abase, const float* __restrict__ Bw,
        const int* __restrict__ cnt, const int* __restrict__ ids,
        const __bf16* __restrict__ Gin, __bf16* __restrict__ Out) {
    const int e  = blockIdx.y;
    const int ct = blockIdx.x;              // tile of 64 cols
    const int n  = cnt[e];
    if (n <= 0) return;

    const int tid  = threadIdx.x;
    const int lane = tid & 63;
    const int w    = tid >> 6;
    const int g16  = lane >> 4;
    const int l16  = lane & 15;

    __shared__ __align__(16) char lds[3][16384];
    // buffer: A bf16 [chunk4][row128]x16B @0 (8KB) | B f32 [k32][col64] @8192 (8KB)

    // B staging: thread covers k-row (tid>>4)+16j, 16B unit tid&15 (256B/row)
    const float* bsrc = Bw + (size_t)e * KDIM * BSTR
                      + (size_t)(tid >> 4) * BSTR + ct * 64 + (tid & 15) * 4;
    const int ach = tid >> 7;               // A chunks: ach, ach+2
    const int arw = tid & 127;
    const int col = ct * 64 + w * 16 + l16;

    for (int mt = 0; mt * 128 < n; mt++) {
        const int ap  = mt * 128 + arw;
        const int aid = ids[(size_t)e * T_TOK + (ap < n ? ap : n - 1)];
        const __bf16* asrc = Abase + (size_t)(MODE < 2 ? (aid >> 3) : aid) * ASTR;

        f32x4 acc[8];
        #pragma unroll
        for (int m = 0; m < 8; m++) { acc[m][0]=0.f; acc[m][1]=0.f; acc[m][2]=0.f; acc[m][3]=0.f; }

        auto stage = [&](int buf, int ks) {   // exactly 4 gll per thread
            char* L = lds[buf];
            gll16(asrc + ks * 32 + ach * 8,        L + ach * 2048 + arw * 16);
            gll16(asrc + ks * 32 + (ach + 2) * 8,  L + (ach + 2) * 2048 + arw * 16);
            gll16(bsrc + (size_t)(ks * 32) * BSTR,      L + 8192 + tid * 16);
            gll16(bsrc + (size_t)(ks * 32 + 16) * BSTR, L + 8192 + 4096 + tid * 16);
        };
        auto consume = [&](int buf) {
            const char* L = lds[buf];
            const float* Bf = (const float*)(L + 8192);
            bf16x8 bf;
            #pragma unroll
            for (int i = 0; i < 8; i++)
                bf[i] = (__bf16)Bf[(g16 * 8 + i) * 64 + w * 16 + l16];
            #pragma unroll
            for (int m = 0; m < 8; m++) {
                bf16x8 af = __builtin_bit_cast(bf16x8,
                    *(const uint4*)(L + g16 * 2048 + (m * 16 + l16) * 16));
                acc[m] = __builtin_amdgcn_mfma_f32_16x16x32_bf16(af, bf, acc[m], 0, 0, 0);
            }
        };

        // prologue: fill ring (12 gll outstanding)
        stage(0, 0); stage(1, 1); stage(2, 2);

        constexpr int NK = KDIM / 32;
        for (int ks = 0; ks < NK - 3; ks++) {
            PIPE_STEP(8, ks % 3, true, ks + 3);
        }
        PIPE_STEP(8, (NK - 3) % 3, false, 0);
        PIPE_STEP(4, (NK - 2) % 3, false, 0);
        PIPE_STEP(0, (NK - 1) % 3, false, 0);

        // epilogue
        #pragma unroll
        for (int m = 0; m < 8; m++) {
            #pragma unroll
            for (int r = 0; r < 4; r++) {
                const int p = mt * 128 + m * 16 + g16 * 4 + r;
                if (p < n) {
                    const int rid = ids[(size_t)e * T_TOK + p];
                    float v = acc[m][r];
                    if (MODE == 1) {
                        const float g = (float)Gin[(size_t)rid * BSTR + col];
                        v *= g / (1.f + __expf(-g));
                    }
                    Out[(size_t)rid * BSTR + col] = (__bf16)v;
                }
            }
        }
    }
}

// ---------------- combine: out[t] = sum_k w[t,k] * Y[t*8+k] ----------------
__global__ __launch_bounds__(256) void combine_kernel(
        const __bf16* __restrict__ Y, const float* __restrict__ pw,
        float* __restrict__ out) {
    const int t   = blockIdx.x;
    const int tid = threadIdx.x;
    const int d0  = tid * 8;
    float acc[8];
    #pragma unroll
    for (int j = 0; j < 8; j++) acc[j] = 0.f;
    #pragma unroll
    for (int k = 0; k < K_TOP; k++) {
        const float wgt = pw[t * K_TOP + k];
        bf16x8 v = *(const bf16x8*)(Y + (size_t)(t * K_TOP + k) * D_DIM + d0);
        #pragma unroll
        for (int j = 0; j < 8; j++) acc[j] += wgt * (float)v[j];
    }
    #pragma unroll
    for (int j = 0; j < 8; j++) out[(size_t)t * D_DIM + d0 + j] = acc[j];
}

extern "C" void kernel_launch(void* const* d_in, const int* in_sizes, int n_in,
                              void* d_out, int out_size, void* d_ws, size_t ws_size,
                              hipStream_t stream) {
    const float* x      = (const float*)d_in[0];
    const float* gw     = (const float*)d_in[1];
    const float* w_gate = (const float*)d_in[2];
    const float* w_up   = (const float*)d_in[3];
    const float* w_down = (const float*)d_in[4];
    float* out = (float*)d_out;

    char* ws = (char*)d_ws;
    int*    cnt = (int*)(ws);
    int*    ids = (int*)(ws + WS_IDS);
    float*  pw  = (float*)(ws + WS_PW);
    __bf16* xbf = (__bf16*)(ws + WS_XBF);
    __bf16* H   = (__bf16*)(ws + WS_H);
    __bf16* Y   = (__bf16*)(ws + WS_Y);
    __bf16* G   = (__bf16*)(ws + WS_Y);   // aliases Y: dead before mlp2 writes

    zero_cnt_kernel<<<1, 64, 0, stream>>>(cnt);
    xcvt_kernel<<<T_TOK * D_DIM / (256 * 8), 256, 0, stream>>>(x, xbf);
    router_kernel<<<T_TOK, 256, 0, stream>>>(x, gw, pw, cnt, ids);
    // gate pass: G = X @ Wg            (768 blocks = exactly 3/CU, all resident)
    gemm_kernel<D_DIM, D_DIM, F_DIM, 0><<<dim3(F_DIM / 64, E_NUM), 256, 0, stream>>>(
        xbf, w_gate, cnt, ids, nullptr, G);
    // up pass:   H = silu(G) * (X @ Wu)
    gemm_kernel<D_DIM, D_DIM, F_DIM, 1><<<dim3(F_DIM / 64, E_NUM), 256, 0, stream>>>(
        xbf, w_up, cnt, ids, G, H);
    // down pass: Y = H @ Wd
    gemm_kernel<F_DIM, F_DIM, D_DIM, 2><<<dim3(D_DIM / 64, E_NUM), 256, 0, stream>>>(
        H, w_down, cnt, ids, nullptr, Y);
    combine_kernel<<<T_TOK, 256, 0, stream>>>(Y, pw, out);
}

// Round 8
// 363.517 us; speedup vs baseline: 1.8134x; 1.0592x over previous
//
#include <hip/hip_runtime.h>
#include <hip/hip_bf16.h>

// Problem constants: T=512 tokens, D=2048 hidden, E=64 experts, K=8 top-k, F=768.
#define T_TOK 512
#define D_DIM 2048
#define E_NUM 64
#define K_TOP 8
#define F_DIM 768

typedef __bf16 bf16x8 __attribute__((ext_vector_type(8)));
typedef float  f32x4  __attribute__((ext_vector_type(4)));

#define AS1 __attribute__((address_space(1)))
#define AS3 __attribute__((address_space(3)))

// async global->LDS, 16B/lane; LDS dest = wave-uniform base + lane*16.
__device__ __forceinline__ void gll16(const void* g, void* l) {
    __builtin_amdgcn_global_load_lds((const AS1 uint32_t*)g, (AS3 uint32_t*)l, 16, 0, 0);
}

#define VM_WAIT_I(N) asm volatile("s_waitcnt vmcnt(" #N ")" ::: "memory")
#define VM_WAIT(N) VM_WAIT_I(N)

// wait for step's 4 glls, sync, consume, sync, optionally stage next step.
#define PIPE_STEP(WN, BUF, DOSTG, KN)            \
    do {                                          \
        VM_WAIT(WN);                              \
        __builtin_amdgcn_sched_barrier(0);        \
        __builtin_amdgcn_s_barrier();             \
        consume(BUF);                             \
        __builtin_amdgcn_s_barrier();             \
        __builtin_amdgcn_sched_barrier(0);        \
        if (DOSTG) stage(BUF, KN);                \
    } while (0)

// ---------------- workspace layout (bytes) ----------------
// cnt  : int[64]          @ 0
// ids  : int[64*512]      @ 4096
// pw   : float[4096]      @ 139264
// Xbf  : bf16[512*2048]   @ 155648   (2 MB)
// H    : bf16[4096*768]   @ 2252800  (6 MB)
// Y    : bf16[4096*2048]  @ 8544256  (16 MB)
// G    : bf16[4096*768]   aliases Y (G is dead before mlp2 writes Y)
#define WS_IDS   4096
#define WS_PW    139264
#define WS_XBF   155648
#define WS_H     2252800
#define WS_Y     8544256

__global__ void zero_cnt_kernel(int* __restrict__ cnt) {
    if (threadIdx.x < E_NUM) cnt[threadIdx.x] = 0;
}

// X fp32 -> bf16 pre-pass
__global__ __launch_bounds__(256) void xcvt_kernel(
        const float* __restrict__ x, __bf16* __restrict__ xb) {
    const size_t i = ((size_t)blockIdx.x * 256 + threadIdx.x) * 8;
    const float4 a = *(const float4*)(x + i);
    const float4 b = *(const float4*)(x + i + 4);
    bf16x8 v;
    v[0]=(__bf16)a.x; v[1]=(__bf16)a.y; v[2]=(__bf16)a.z; v[3]=(__bf16)a.w;
    v[4]=(__bf16)b.x; v[5]=(__bf16)b.y; v[6]=(__bf16)b.z; v[7]=(__bf16)b.w;
    *(uint4*)(xb + i) = __builtin_bit_cast(uint4, v);
}

// ---------------- router: logits -> softmax -> top-8 -> renorm ----------------
// Vectorized: thread (c=tid>>4, g=tid&15) accumulates float4 over experts
// g*4..g*4+3 for k-chunk c (128 k). gw loads are float4; x scalar (L1 hit,
// shared by the 16 g-threads). LDS reduce -> wave 0 does top-8.
__global__ __launch_bounds__(256) void router_kernel(
        const float* __restrict__ x, const float* __restrict__ gw,
        float* __restrict__ pair_w, int* __restrict__ cnt, int* __restrict__ ids) {
    const int t   = blockIdx.x;
    const int tid = threadIdx.x;
    const int c   = tid >> 4;   // 16 k-chunks of 128
    const int g   = tid & 15;   // float4 expert group

    const float* xr  = x + (size_t)t * D_DIM + c * 128;
    const float4* gr = (const float4*)(gw + (size_t)(c * 128) * E_NUM + g * 4);

    f32x4 acc; acc[0]=0.f; acc[1]=0.f; acc[2]=0.f; acc[3]=0.f;
    #pragma unroll 8
    for (int k = 0; k < 128; k++) {
        const float xv = xr[k];
        const float4 wv = gr[(size_t)k * 16];
        acc[0] += xv * wv.x; acc[1] += xv * wv.y;
        acc[2] += xv * wv.z; acc[3] += xv * wv.w;
    }
    __shared__ f32x4 part[16][16];
    part[c][g] = acc;
    __syncthreads();
    if (tid < 64) {  // lane == e
        const int e = tid;
        float logit = 0.f;
        #pragma unroll
        for (int cc = 0; cc < 16; cc++) logit += part[cc][e >> 2][e & 3];
        float cur = logit;
        float selV[8]; int selE[8];
        #pragma unroll
        for (int i = 0; i < 8; i++) {
            float bv = cur; int bi = e;
            #pragma unroll
            for (int off = 32; off > 0; off >>= 1) {
                float ov = __shfl_xor(bv, off);
                int   oi = __shfl_xor(bi, off);
                if (ov > bv || (ov == bv && oi < bi)) { bv = ov; bi = oi; }
            }
            selV[i] = bv; selE[i] = bi;
            if (e == bi) cur = -INFINITY;
        }
        const float m = selV[0];
        float sum = 0.f;
        #pragma unroll
        for (int i = 0; i < 8; i++) sum += __expf(selV[i] - m);
        float myW = 0.f; int myE = 0;
        #pragma unroll
        for (int i = 0; i < 8; i++) {
            if (e == i) { myW = __expf(selV[i] - m) / sum; myE = selE[i]; }
        }
        if (e < 8) {
            pair_w[t * K_TOP + e] = myW;
            int pos = atomicAdd(&cnt[myE], 1);
            ids[myE * T_TOK + pos] = t * K_TOP + e;  // token = id>>3
        }
    }
}

// ================= unified expert GEMM pass =================
// C[rows n][64-col tile] = A[rows][KDIM] @ B_e[KDIM][BSTR], BM=128, BK=32.
// Ring-3 LDS (48 KB -> 3 blocks/CU), 4 gll/step (A 2 + B 2), steady vmcnt(8)
// = 2 full k-steps in flight. B k-row = 64 f32 = 256 B = one DRAM granule.
// XCD-aware bijective swizzle (T1): each XCD owns a contiguous run of
// experts -> its L2 streams whole weight matrices (full 3KB rows) instead of
// a strided 1/8-column subset. nwg%8==0 for both grids.
// MODE 0: Out = acc (gate -> G); 1: Out = silu(Gin)*acc (up -> H); 2: acc (down -> Y).
template<int KDIM, int ASTR, int BSTR, int MODE>
__global__ __launch_bounds__(256, 3) void gemm_kernel(
        const __bf16* __restrict__ Abase, const float* __restrict__ Bw,
        const int* __restrict__ cnt, const int* __restrict__ ids,
        const __bf16* __restrict__ Gin, __bf16* __restrict__ Out) {
    constexpr int NCT = BSTR / 64;
    constexpr int NWG = NCT * E_NUM;
    constexpr int CHK = NWG / 8;
    const int bid = blockIdx.y * NCT + blockIdx.x;
    const int wg  = (bid & 7) * CHK + (bid >> 3);   // XCD-contiguous work id
    const int e   = wg / NCT;
    const int ct  = wg % NCT;
    const int n = cnt[e];
    if (n <= 0) return;

    const int tid  = threadIdx.x;
    const int lane = tid & 63;
    const int w    = tid >> 6;
    const int g16  = lane >> 4;
    const int l16  = lane & 15;

    __shared__ __align__(16) char lds[3][16384];
    // buffer: A bf16 [chunk4][row128]x16B @0 (8KB) | B f32 [k32][col64] @8192 (8KB)

    // B staging: thread covers k-row (tid>>4)+16j, 16B unit tid&15 (256B/row)
    const float* bsrc = Bw + (size_t)e * KDIM * BSTR
                      + (size_t)(tid >> 4) * BSTR + ct * 64 + (tid & 15) * 4;
    const int ach = tid >> 7;               // A chunks: ach, ach+2
    const int arw = tid & 127;
    const int col = ct * 64 + w * 16 + l16;

    for (int mt = 0; mt * 128 < n; mt++) {
        const int ap  = mt * 128 + arw;
        const int aid = ids[(size_t)e * T_TOK + (ap < n ? ap : n - 1)];
        const __bf16* asrc = Abase + (size_t)(MODE < 2 ? (aid >> 3) : aid) * ASTR;

        f32x4 acc[8];
        #pragma unroll
        for (int m = 0; m < 8; m++) { acc[m][0]=0.f; acc[m][1]=0.f; acc[m][2]=0.f; acc[m][3]=0.f; }

        auto stage = [&](int buf, int ks) {   // exactly 4 gll per thread
            char* L = lds[buf];
            gll16(asrc + ks * 32 + ach * 8,        L + ach * 2048 + arw * 16);
            gll16(asrc + ks * 32 + (ach + 2) * 8,  L + (ach + 2) * 2048 + arw * 16);
            gll16(bsrc + (size_t)(ks * 32) * BSTR,      L + 8192 + tid * 16);
            gll16(bsrc + (size_t)(ks * 32 + 16) * BSTR, L + 8192 + 4096 + tid * 16);
        };
        auto consume = [&](int buf) {
            const char* L = lds[buf];
            const float* Bf = (const float*)(L + 8192);
            bf16x8 bf;
            #pragma unroll
            for (int i = 0; i < 8; i++)
                bf[i] = (__bf16)Bf[(g16 * 8 + i) * 64 + w * 16 + l16];
            #pragma unroll
            for (int m = 0; m < 8; m++) {
                bf16x8 af = __builtin_bit_cast(bf16x8,
                    *(const uint4*)(L + g16 * 2048 + (m * 16 + l16) * 16));
                acc[m] = __builtin_amdgcn_mfma_f32_16x16x32_bf16(af, bf, acc[m], 0, 0, 0);
            }
        };

        // prologue: fill ring (12 gll outstanding)
        stage(0, 0); stage(1, 1); stage(2, 2);

        constexpr int NK = KDIM / 32;
        for (int ks = 0; ks < NK - 3; ks++) {
            PIPE_STEP(8, ks % 3, true, ks + 3);
        }
        PIPE_STEP(8, (NK - 3) % 3, false, 0);
        PIPE_STEP(4, (NK - 2) % 3, false, 0);
        PIPE_STEP(0, (NK - 1) % 3, false, 0);

        // epilogue
        #pragma unroll
        for (int m = 0; m < 8; m++) {
            #pragma unroll
            for (int r = 0; r < 4; r++) {
                const int p = mt * 128 + m * 16 + g16 * 4 + r;
                if (p < n) {
                    const int rid = ids[(size_t)e * T_TOK + p];
                    float v = acc[m][r];
                    if (MODE == 1) {
                        const float g = (float)Gin[(size_t)rid * BSTR + col];
                        v *= g / (1.f + __expf(-g));
                    }
                    Out[(size_t)rid * BSTR + col] = (__bf16)v;
                }
            }
        }
    }
}

// ---------------- combine: out[t] = sum_k w[t,k] * Y[t*8+k] ----------------
__global__ __launch_bounds__(256) void combine_kernel(
        const __bf16* __restrict__ Y, const float* __restrict__ pw,
        float* __restrict__ out) {
    const int t   = blockIdx.x;
    const int tid = threadIdx.x;
    const int d0  = tid * 8;
    float acc[8];
    #pragma unroll
    for (int j = 0; j < 8; j++) acc[j] = 0.f;
    #pragma unroll
    for (int k = 0; k < K_TOP; k++) {
        const float wgt = pw[t * K_TOP + k];
        bf16x8 v = *(const bf16x8*)(Y + (size_t)(t * K_TOP + k) * D_DIM + d0);
        #pragma unroll
        for (int j = 0; j < 8; j++) acc[j] += wgt * (float)v[j];
    }
    #pragma unroll
    for (int j = 0; j < 8; j++) out[(size_t)t * D_DIM + d0 + j] = acc[j];
}

extern "C" void kernel_launch(void* const* d_in, const int* in_sizes, int n_in,
                              void* d_out, int out_size, void* d_ws, size_t ws_size,
                              hipStream_t stream) {
    const float* x      = (const float*)d_in[0];
    const float* gw     = (const float*)d_in[1];
    const float* w_gate = (const float*)d_in[2];
    const float* w_up   = (const float*)d_in[3];
    const float* w_down = (const float*)d_in[4];
    float* out = (float*)d_out;

    char* ws = (char*)d_ws;
    int*    cnt = (int*)(ws);
    int*    ids = (int*)(ws + WS_IDS);
    float*  pw  = (float*)(ws + WS_PW);
    __bf16* xbf = (__bf16*)(ws + WS_XBF);
    __bf16* H   = (__bf16*)(ws + WS_H);
    __bf16* Y   = (__bf16*)(ws + WS_Y);
    __bf16* G   = (__bf16*)(ws + WS_Y);   // aliases Y: dead before mlp2 writes

    zero_cnt_kernel<<<1, 64, 0, stream>>>(cnt);
    xcvt_kernel<<<T_TOK * D_DIM / (256 * 8), 256, 0, stream>>>(x, xbf);
    router_kernel<<<T_TOK, 256, 0, stream>>>(x, gw, pw, cnt, ids);
    // gate pass: G = X @ Wg            (768 blocks = exactly 3/CU, all resident)
    gemm_kernel<D_DIM, D_DIM, F_DIM, 0><<<dim3(F_DIM / 64, E_NUM), 256, 0, stream>>>(
        xbf, w_gate, cnt, ids, nullptr, G);
    // up pass:   H = silu(G) * (X @ Wu)
    gemm_kernel<D_DIM, D_DIM, F_DIM, 1><<<dim3(F_DIM / 64, E_NUM), 256, 0, stream>>>(
        xbf, w_up, cnt, ids, G, H);
    // down pass: Y = H @ Wd
    gemm_kernel<F_DIM, F_DIM, D_DIM, 2><<<dim3(D_DIM / 64, E_NUM), 256, 0, stream>>>(
        H, w_down, cnt, ids, nullptr, Y);
    combine_kernel<<<T_TOK, 256, 0, stream>>>(Y, pw, out);
}